// Round 3
// baseline (339.827 us; speedup 1.0000x reference)
//
#include <hip/hip_runtime.h>
#include <hip/hip_bf16.h>

using bf16 = __hip_bfloat16;

#define DI __device__ __forceinline__

typedef __attribute__((ext_vector_type(8))) short short8;
typedef __attribute__((ext_vector_type(8))) unsigned short u16x8;
typedef __attribute__((ext_vector_type(4))) unsigned short u16x4;
typedef __attribute__((ext_vector_type(4))) float f32x4;

#define MFMA_BF16 __builtin_amdgcn_mfma_f32_16x16x32_bf16

DI float leaky(float x) { return x > 0.f ? x : 0.1f * x; }

// bf16 split helpers (RNE). x = hi + lo to ~2^-16 relative.
DI unsigned short b16(float x) {
  union { float f; unsigned u; } v; v.f = x;
  unsigned r = v.u + 0x7FFFu + ((v.u >> 16) & 1u);
  return (unsigned short)(r >> 16);
}
DI float fromb16(unsigned short h) {
  union { unsigned u; float f; } v; v.u = ((unsigned)h) << 16; return v.f;
}

// Problem constants: B=2, C=64, H=64, W=64, N=4096. Inputs fp32 (R3/R4).
// NOTE R13: hipLaunchCooperativeKernel fails silently under graph capture here.
// Precision ladder (validated): Q/K split bf16 (required — logits feed exp),
// P hi-only (R12: absmax 9.8e-4), V hi-only in PV, L via ones-row MFMA (R0').
// R2: swapped QK^T -> lane owns one pixel; 2 shfl_xor softmax.
// R3: convs rewritten barrier-free: wave owns output row(s), lane = pixel,
// +-1 column taps via shfl_up/down (masked at lane 0/63 = zero-pad), weights
// broadcast from LDS float4 (4 oc/block). Kills 66 barriers/block, LDS tile,
// bank conflicts (R2 counters: 3.24M conflict cycles, 62% issue-idle).
static constexpr int N_ = 4096;
static constexpr size_t CN = 262144;
static constexpr size_t BCN = 524288;

// ---- Workspace layout (float indices) ----
static constexpr size_t XG_OFF = 137104;
static constexpr size_t GG_OFF = XG_OFF + BCN;
static constexpr size_t QX_OFF = GG_OFF + BCN;
static constexpr size_t KX_OFF = QX_OFF + BCN;
static constexpr size_t VX_OFF = KX_OFF + BCN;
static constexpr size_t QG_OFF = VX_OFF + BCN;
static constexpr size_t KG_OFF = QG_OFF + BCN;
static constexpr size_t P1X_OFF = KG_OFF + BCN;
static constexpr size_t P1G_OFF = P1X_OFF + BCN;
static constexpr size_t ML_OFF  = P1G_OFF + BCN;
static constexpr size_t MLL_OFF = ML_OFF + 32768;
static constexpr size_t OB_OFF = QX_OFF;
static constexpr size_t UB_OFF = KX_OFF;
static constexpr size_t GO_OFF = GG_OFF;
static constexpr size_t QXH_U = QX_OFF * 2, QXL_U = QXH_U + BCN;
static constexpr size_t KXH_U = KX_OFF * 2, KXL_U = KXH_U + BCN;
static constexpr size_t VXH_U = VX_OFF * 2;
static constexpr size_t QGH_U = QG_OFF * 2, QGL_U = QGH_U + BCN;
static constexpr size_t KGH_U = KG_OFF * 2, KGL_U = KGH_U + BCN;
// Peak 19.7 MB (validated R6-R14)

// ---------------- K1: coord-conv 3x3, barrier-free, wave = 2 rows, 4 oc/block ----------------
__global__ __launch_bounds__(256) void k_coordconv(const float* __restrict__ x,
                                                   const float* __restrict__ g,
                                                   const float* __restrict__ lw_p,
                                                   const float* __restrict__ lb_p,
                                                   const float* __restrict__ cw,
                                                   float* __restrict__ ws) {
  int blk = blockIdx.x;  // 512 = src*256 + b*128 + og*8 + rt
  int rt = blk & 7;   blk >>= 3;
  int og = blk & 15;  blk >>= 4;
  int b  = blk & 1;   blk >>= 1;
  int src = blk;
  int o0 = og * 4;
  const float* in = src ? g : x;
  float* outp = ws + (src ? GG_OFF : XG_OFF);
  __shared__ __align__(16) float4 wl4[594];   // [ch*9+tap] -> 4 oc
  __shared__ float sCA[4];
  int t = threadIdx.x;
  int wv = t >> 6, px = t & 63;

  // channel attention: wave wv computes mean of channel o0+wv
  {
    const float* chp = in + ((size_t)(b * 64 + o0 + wv)) * N_;
    float s = 0.f;
    for (int i = px; i < N_; i += 64) s += chp[i];
#pragma unroll
    for (int d = 1; d < 64; d <<= 1) s += __shfl_xor(s, d, 64);
    if (px == 0) {
      float p = s * (1.f / (float)N_);
      float lwv = lw_p[0], lbv = lb_p[0];
      float h = leaky(lwv * p + lbv);
      sCA[wv] = 1.f / (1.f + expf(-(lwv * h + lbv)));
    }
  }
  {
    float* wlf = (float*)wl4;
    for (int idx = t; idx < 2376; idx += 256)
      wlf[idx] = cw[(size_t)(o0 + (idx & 3)) * 594 + (idx >> 2)];
  }
  __syncthreads();

  int r0 = rt * 8 + wv * 2;     // wave owns out rows r0, r0+1
  auto ldrow = [&](int ch, int rr) -> float {
    if (rr < 0 || rr > 63) return 0.f;
    if (ch < 64) return in[((size_t)(b * 64 + ch)) * N_ + (size_t)rr * 64 + px];
    if (ch == 64) return (float)px * (2.f / 63.f) - 1.f;
    return (float)rr * (2.f / 63.f) - 1.f;
  };

  float cur[4], nxt[4];
#pragma unroll
  for (int i = 0; i < 4; ++i) cur[i] = ldrow(0, r0 - 1 + i);
  float acc[2][4] = {};
  for (int ch = 0; ch < 66; ++ch) {
    if (ch + 1 < 66) {
#pragma unroll
      for (int i = 0; i < 4; ++i) nxt[i] = ldrow(ch + 1, r0 - 1 + i);
    }
    float lf[4], rg[4];
#pragma unroll
    for (int i = 0; i < 4; ++i) {
      lf[i] = __shfl_up(cur[i], 1, 64);   if (px == 0)  lf[i] = 0.f;
      rg[i] = __shfl_down(cur[i], 1, 64); if (px == 63) rg[i] = 0.f;
    }
#pragma unroll
    for (int ky = 0; ky < 3; ++ky) {
      float4 w0 = wl4[ch * 9 + ky * 3 + 0];
      float4 w1 = wl4[ch * 9 + ky * 3 + 1];
      float4 w2 = wl4[ch * 9 + ky * 3 + 2];
#pragma unroll
      for (int j = 0; j < 2; ++j) {
        int ir = j + ky;
        acc[j][0] = fmaf(w0.x, lf[ir], fmaf(w1.x, cur[ir], fmaf(w2.x, rg[ir], acc[j][0])));
        acc[j][1] = fmaf(w0.y, lf[ir], fmaf(w1.y, cur[ir], fmaf(w2.y, rg[ir], acc[j][1])));
        acc[j][2] = fmaf(w0.z, lf[ir], fmaf(w1.z, cur[ir], fmaf(w2.z, rg[ir], acc[j][2])));
        acc[j][3] = fmaf(w0.w, lf[ir], fmaf(w1.w, cur[ir], fmaf(w2.w, rg[ir], acc[j][3])));
      }
    }
#pragma unroll
    for (int i = 0; i < 4; ++i) cur[i] = nxt[i];
  }
  float s0 = sCA[0], s1 = sCA[1], s2 = sCA[2], s3 = sCA[3];
#pragma unroll
  for (int j = 0; j < 2; ++j) {
    size_t pix = (size_t)(r0 + j) * 64 + px;
    outp[((size_t)(b * 64 + o0 + 0)) * N_ + pix] = acc[j][0] * s0;
    outp[((size_t)(b * 64 + o0 + 1)) * N_ + pix] = acc[j][1] * s1;
    outp[((size_t)(b * 64 + o0 + 2)) * N_ + pix] = acc[j][2] * s2;
    outp[((size_t)(b * 64 + o0 + 3)) * N_ + pix] = acc[j][3] * s3;
  }
}

// ---------------- K2: 1x1 projections; Q/K pre-split hi/lo, V hi-only transposed ----------------
__global__ __launch_bounds__(256) void k_proj(float* __restrict__ ws,
                                              const float* __restrict__ xqw, const float* __restrict__ xqb,
                                              const float* __restrict__ xkw, const float* __restrict__ xkb,
                                              const float* __restrict__ xvw, const float* __restrict__ xvb,
                                              const float* __restrict__ gqw, const float* __restrict__ gqb,
                                              const float* __restrict__ gkw, const float* __restrict__ gkb) {
  int blk = blockIdx.x;  // 5 * 2 * 64
  int pt = blk & 63; blk >>= 6;
  int b  = blk & 1;  blk >>= 1;
  int which = blk;
  size_t in_o;
  const float *wp, *bp;
  size_t hU = 0, lU = 0;
  if (which == 0)      { in_o = XG_OFF; wp = xqw; bp = xqb; hU = QXH_U; lU = QXL_U; }
  else if (which == 1) { in_o = XG_OFF; wp = xkw; bp = xkb; hU = KXH_U; lU = KXL_U; }
  else if (which == 2) { in_o = XG_OFF; wp = xvw; bp = xvb; }
  else if (which == 3) { in_o = GG_OFF; wp = gqw; bp = gqb; hU = QGH_U; lU = QGL_U; }
  else                 { in_o = GG_OFF; wp = gkw; bp = gkb; hU = KGH_U; lU = KGL_U; }

  __shared__ float tile[64 * 64];
  __shared__ float wl[64 * 65];
  __shared__ float bl[64];
  unsigned short* us = (unsigned short*)ws;
  int t = threadIdx.x;
  int pb = pt * 64;
  const float* in0 = ws + in_o + (size_t)b * CN + pb;
  for (int c0 = (t >> 6); c0 < 64; c0 += 4)
    tile[c0 * 64 + (t & 63)] = in0[(size_t)c0 * N_ + (t & 63)];
  for (int idx = t; idx < 4096; idx += 256)
    wl[(idx >> 6) * 65 + (idx & 63)] = wp[idx];
  if (t < 64) bl[t] = bp[t];
  __syncthreads();
  int o = t & 63, grp = t >> 6;
  const float* wr = &wl[o * 65];
  float acc[16];
  float bv = bl[o];
#pragma unroll
  for (int j = 0; j < 16; ++j) acc[j] = bv;
  for (int c = 0; c < 64; ++c) {
    float wv = wr[c];
    const float4* tb = reinterpret_cast<const float4*>(&tile[c * 64 + grp * 16]);
    float4 t0 = tb[0], t1 = tb[1], t2 = tb[2], t3 = tb[3];
    acc[0] = fmaf(wv, t0.x, acc[0]);   acc[1] = fmaf(wv, t0.y, acc[1]);
    acc[2] = fmaf(wv, t0.z, acc[2]);   acc[3] = fmaf(wv, t0.w, acc[3]);
    acc[4] = fmaf(wv, t1.x, acc[4]);   acc[5] = fmaf(wv, t1.y, acc[5]);
    acc[6] = fmaf(wv, t1.z, acc[6]);   acc[7] = fmaf(wv, t1.w, acc[7]);
    acc[8] = fmaf(wv, t2.x, acc[8]);   acc[9] = fmaf(wv, t2.y, acc[9]);
    acc[10] = fmaf(wv, t2.z, acc[10]); acc[11] = fmaf(wv, t2.w, acc[11]);
    acc[12] = fmaf(wv, t3.x, acc[12]); acc[13] = fmaf(wv, t3.y, acc[13]);
    acc[14] = fmaf(wv, t3.z, acc[14]); acc[15] = fmaf(wv, t3.w, acc[15]);
  }
  if (which != 2) {
#pragma unroll
    for (int j = 0; j < 16; ++j) {
      size_t idx = ((size_t)b * N_ + pb + grp * 16 + j) * 64 + o;
      unsigned short hi = b16(acc[j]);
      us[hU + idx] = hi;
      us[lU + idx] = b16(acc[j] - fromb16(hi));
    }
  } else {
    __syncthreads();
    float* ot = wl;
#pragma unroll
    for (int j = 0; j < 16; ++j) ot[o * 65 + grp * 16 + j] = acc[j];
    __syncthreads();
    int o2 = t >> 2;
#pragma unroll
    for (int e = 0; e < 4; ++e) {
      int px = (t & 3) * 16 + e * 4;
      u16x4 hv;
#pragma unroll
      for (int q = 0; q < 4; ++q) hv[q] = b16(ot[o2 * 65 + px + q]);
      size_t idx = ((size_t)(b * 64 + o2)) * N_ + pb + px;
      *reinterpret_cast<u16x4*>(&us[VXH_U + idx]) = hv;
    }
  }
}

// ---------------- K3: MFMA flash attention (swapped QK^T: lane owns one pixel) ----------------
__global__ __launch_bounds__(256) void k_attn(float* __restrict__ ws) {
  unsigned short* us = (unsigned short*)ws;
  int blk = blockIdx.x;
  int half = blk & 1; blk >>= 1;
  int qt = blk & 63;  blk >>= 6;
  int b  = blk & 1;   blk >>= 1;
  int at = blk;
  const unsigned short* QH = us + (at ? QGH_U : QXH_U);
  const unsigned short* QL = us + (at ? QGL_U : QXL_U);
  const unsigned short* KHg = us + (at ? KGH_U : KXH_U);
  const unsigned short* KLg = us + (at ? KGL_U : KXL_U);
  const unsigned short* VHg = us + VXH_U;
  float* Pg = ws + (at ? (half ? P1G_OFF : GG_OFF) : (half ? P1X_OFF : XG_OFF))
            + (size_t)b * CN + qt * 64;

  __shared__ unsigned short Kh[2][4096], Kl[2][4096], Vth[2][4096], Ph[4096];

  int t = threadIdx.x;
  int w = t >> 6, lane = t & 63, quad = lane >> 4, l15 = lane & 15;
  int swz = l15 & 7;

  short8 qh[2], ql[2];
  {
    size_t qbase = ((size_t)b * N_ + qt * 64 + 16 * w + l15) * 64;
#pragma unroll
    for (int ks = 0; ks < 2; ++ks) {
      qh[ks] = *reinterpret_cast<const short8*>(&QH[qbase + ks * 32 + quad * 8]);
      ql[ks] = *reinterpret_cast<const short8*>(&QL[qbase + ks * 32 + quad * 8]);
    }
  }

  short8 ones;
#pragma unroll
  for (int j = 0; j < 8; ++j) ones[j] = (short)0x3F80;  // bf16 1.0

  int mt0 = half * 32, mt1 = half * 32 + 32;

  u16x8 rkh[2], rkl[2], rvh[2];
  size_t ko = ((size_t)b * N_ + (size_t)mt0 * 64 + (t >> 3)) * 64 + (size_t)(t & 7) * 8;
  size_t vo = ((size_t)(b * 64) + (t >> 3)) * N_ + (size_t)mt0 * 64 + (size_t)(t & 7) * 8;
  auto prefetch = [&]() {
    rkh[0] = *reinterpret_cast<const u16x8*>(&KHg[ko]);
    rkl[0] = *reinterpret_cast<const u16x8*>(&KLg[ko]);
    rkh[1] = *reinterpret_cast<const u16x8*>(&KHg[ko + 2048]);
    rkl[1] = *reinterpret_cast<const u16x8*>(&KLg[ko + 2048]);
    rvh[0] = *reinterpret_cast<const u16x8*>(&VHg[vo]);
    rvh[1] = *reinterpret_cast<const u16x8*>(&VHg[vo + (size_t)32 * N_]);
    ko += 4096; vo += 64;
  };
  int wr0 = t >> 3, wch = t & 7;
  int woff = wr0 * 64 + ((wch ^ (wr0 & 7)) << 3);
  auto writebuf = [&](int par) {
    *reinterpret_cast<u16x8*>(&Kh[par][woff]) = rkh[0];
    *reinterpret_cast<u16x8*>(&Kl[par][woff]) = rkl[0];
    *reinterpret_cast<u16x8*>(&Vth[par][woff]) = rvh[0];
    *reinterpret_cast<u16x8*>(&Kh[par][woff + 2048]) = rkh[1];
    *reinterpret_cast<u16x8*>(&Kl[par][woff + 2048]) = rkl[1];
    *reinterpret_cast<u16x8*>(&Vth[par][woff + 2048]) = rvh[1];
  };

  f32x4 Oa[4] = {{0.f, 0.f, 0.f, 0.f}, {0.f, 0.f, 0.f, 0.f},
                 {0.f, 0.f, 0.f, 0.f}, {0.f, 0.f, 0.f, 0.f}};
  f32x4 La = {0.f, 0.f, 0.f, 0.f};   // L in element 0 (ones-row MFMA; rows identical)
  float M = -1e30f;                  // per-lane: pixel n = 16w + l15

  int phb = (16 * w + l15) * 64;
  int mh = quad >> 1, mlw = (quad & 1) * 4;

  prefetch();
  writebuf(0);
  __syncthreads();
  for (int mt = mt0; mt < mt1; ++mt) {
    int pb = (mt - mt0) & 1;
    if (mt + 1 < mt1) prefetch();  // global latency overlaps tile compute

    // S^T[m][n]: m = ms*16 + quad*4 + reg, n = 16w + l15 (swapped operands)
    f32x4 S[4];
    __builtin_amdgcn_s_setprio(1);
#pragma unroll
    for (int ms = 0; ms < 4; ++ms) {
      f32x4 a0 = {0.f, 0.f, 0.f, 0.f}, a1 = {0.f, 0.f, 0.f, 0.f};
      int row = ms * 16 + l15;
#pragma unroll
      for (int ks = 0; ks < 2; ++ks) {
        int off = row * 64 + (((ks * 4 + quad) ^ swz) << 3);
        short8 khf = *reinterpret_cast<const short8*>(&Kh[pb][off]);
        short8 klf = *reinterpret_cast<const short8*>(&Kl[pb][off]);
        f32x4& a = ks ? a1 : a0;
        a = MFMA_BF16(khf, ql[ks], a, 0, 0, 0);
        a = MFMA_BF16(klf, qh[ks], a, 0, 0, 0);
        a = MFMA_BF16(khf, qh[ks], a, 0, 0, 0);
      }
      S[ms] = a0 + a1;
    }
    __builtin_amdgcn_s_setprio(0);

    // in-lane max over 16 values + 2-step cross-quad butterfly
    float m0 = fmaxf(fmaxf(S[0][0], S[0][1]), fmaxf(S[0][2], S[0][3]));
    float m1 = fmaxf(fmaxf(S[1][0], S[1][1]), fmaxf(S[1][2], S[1][3]));
    float m2 = fmaxf(fmaxf(S[2][0], S[2][1]), fmaxf(S[2][2], S[2][3]));
    float m3 = fmaxf(fmaxf(S[3][0], S[3][1]), fmaxf(S[3][2], S[3][3]));
    float tm = fmaxf(fmaxf(m0, m1), fmaxf(m2, m3));
    tm = fmaxf(tm, __shfl_xor(tm, 16, 64));
    tm = fmaxf(tm, __shfl_xor(tm, 32, 64));
    float mn = fmaxf(M, tm);
    float al = __expf(M - mn);
    M = mn;
#pragma unroll
    for (int ms = 0; ms < 4; ++ms) {
      int goff = phb + ((((ms << 1) + mh) ^ swz) << 3) + mlw;
#pragma unroll
      for (int r = 0; r < 4; ++r) {
        float p = __expf(S[ms][r] - mn);
        Ph[goff + r] = b16(p);   // wave-private rows -> no barrier needed
      }
    }
#pragma unroll
    for (int cs = 0; cs < 4; ++cs) {
      Oa[cs][0] *= al; Oa[cs][1] *= al; Oa[cs][2] *= al; Oa[cs][3] *= al;
    }
    La[0] *= al;

    // O^T += V^T P^T, V hi-only: 10 MFMAs (incl. 2 ones-row for L), 10 ds_reads/tile
    __builtin_amdgcn_s_setprio(1);
#pragma unroll
    for (int ks = 0; ks < 2; ++ks) {
      int poff = phb + (((ks * 4 + quad) ^ swz) << 3);
      short8 phf = *reinterpret_cast<const short8*>(&Ph[poff]);
      La = MFMA_BF16(ones, phf, La, 0, 0, 0);   // row-sums of P == L partials
#pragma unroll
      for (int cs = 0; cs < 4; ++cs) {
        int voff = (cs * 16 + l15) * 64 + (((ks * 4 + quad) ^ swz) << 3);
        short8 vhf = *reinterpret_cast<const short8*>(&Vth[pb][voff]);
        Oa[cs] = MFMA_BF16(vhf, phf, Oa[cs], 0, 0, 0);
      }
    }
    __builtin_amdgcn_s_setprio(0);

    if (mt + 1 < mt1) writebuf(pb ^ 1);  // fenced by previous iteration's barrier
    __syncthreads();
  }

#pragma unroll
  for (int cs = 0; cs < 4; ++cs) {
#pragma unroll
    for (int r = 0; r < 4; ++r) {
      int c = cs * 16 + quad * 4 + r;
      Pg[(size_t)c * N_ + 16 * w + l15] = Oa[cs][r];
    }
  }
  if (quad == 0) {
    int mlb = ((at * 2 + half) * 2 + b) * 4096 + qt * 64 + 16 * w + l15;
    ws[ML_OFF + mlb] = M;
    ws[MLL_OFF + mlb] = La[0];   // La col = pixel 16w+l15, rows identical
  }
}

// ---------------- K4: merge halves + combine ----------------
__global__ __launch_bounds__(256) void k_merge(float* __restrict__ ws,
                                               const float* __restrict__ gm_p,
                                               const float* __restrict__ al_p) {
  size_t i4 = (size_t)blockIdx.x * 256 + threadIdx.x;
  size_t i = i4 * 4;
  int n = (int)(i & 4095);
  int b = (int)(i >> 18);
  float gm = gm_p[0], al = al_p[0];
  float4 p0x = *reinterpret_cast<const float4*>(ws + XG_OFF + i);
  float4 p1x = *reinterpret_cast<const float4*>(ws + P1X_OFF + i);
  float4 p0g = *reinterpret_cast<const float4*>(ws + GG_OFF + i);
  float4 p1g = *reinterpret_cast<const float4*>(ws + P1G_OFF + i);
  float4 M0x = *reinterpret_cast<const float4*>(ws + ML_OFF  + (0 + b) * 4096 + n);
  float4 L0x = *reinterpret_cast<const float4*>(ws + MLL_OFF + (0 + b) * 4096 + n);
  float4 M1x = *reinterpret_cast<const float4*>(ws + ML_OFF  + (2 + b) * 4096 + n);
  float4 L1x = *reinterpret_cast<const float4*>(ws + MLL_OFF + (2 + b) * 4096 + n);
  float4 M0g = *reinterpret_cast<const float4*>(ws + ML_OFF  + (4 + b) * 4096 + n);
  float4 L0g = *reinterpret_cast<const float4*>(ws + MLL_OFF + (4 + b) * 4096 + n);
  float4 M1g = *reinterpret_cast<const float4*>(ws + ML_OFF  + (6 + b) * 4096 + n);
  float4 L1g = *reinterpret_cast<const float4*>(ws + MLL_OFF + (6 + b) * 4096 + n);
  const float* p0xv = (const float*)&p0x; const float* p1xv = (const float*)&p1x;
  const float* p0gv = (const float*)&p0g; const float* p1gv = (const float*)&p1g;
  const float* m0xv = (const float*)&M0x; const float* l0xv = (const float*)&L0x;
  const float* m1xv = (const float*)&M1x; const float* l1xv = (const float*)&L1x;
  const float* m0gv = (const float*)&M0g; const float* l0gv = (const float*)&L0g;
  const float* m1gv = (const float*)&M1g; const float* l1gv = (const float*)&L1g;
  float4 go, ob;
  float* gov = (float*)&go; float* obv = (float*)&ob;
#pragma unroll
  for (int l = 0; l < 4; ++l) {
    float mx = fmaxf(m0xv[l], m1xv[l]);
    float w0 = __expf(m0xv[l] - mx), w1 = __expf(m1xv[l] - mx);
    float xc = (p0xv[l] * w0 + p1xv[l] * w1) / (l0xv[l] * w0 + l1xv[l] * w1);
    float mg = fmaxf(m0gv[l], m1gv[l]);
    float v0 = __expf(m0gv[l] - mg), v1 = __expf(m1gv[l] - mg);
    float gc = (p0gv[l] * v0 + p1gv[l] * v1) / (l0gv[l] * v0 + l1gv[l] * v1);
    gov[l] = gc;
    obv[l] = gm * xc + al * gc;
  }
  *reinterpret_cast<float4*>(ws + GG_OFF + i) = go;  // GO
  *reinterpret_cast<float4*>(ws + QX_OFF + i) = ob;  // OB
}

// ---------------- K5: u = leaky(conv3x3(leaky(out), c1)), barrier-free, wave = 1 row, 4 oc ----------------
__global__ __launch_bounds__(128) void k_conv1(float* __restrict__ ws,
                                               const float* __restrict__ c1w,
                                               const float* __restrict__ c1b) {
  int blk = blockIdx.x;  // 1024 = b*512 + og*32 + rt
  int rt = blk & 31; blk >>= 5;
  int og = blk & 15; blk >>= 4;
  int b  = blk;
  int o0 = og * 4;
  __shared__ __align__(16) float4 wl4[576];
  int t = threadIdx.x;
  int wv = t >> 6, px = t & 63;
  {
    float* wlf = (float*)wl4;
    for (int idx = t; idx < 2304; idx += 128)
      wlf[idx] = c1w[(size_t)(o0 + (idx & 3)) * 576 + (idx >> 2)];
  }
  __syncthreads();

  const float* in0 = ws + OB_OFF + (size_t)b * CN;
  int r0 = rt * 2 + wv;   // wave owns out row r0
  auto ldrow = [&](int ch, int rr) -> float {
    if (rr < 0 || rr > 63) return 0.f;
    return leaky(in0[(size_t)ch * N_ + (size_t)rr * 64 + px]);
  };
  float cur[3], nxt[3];
#pragma unroll
  for (int i = 0; i < 3; ++i) cur[i] = ldrow(0, r0 - 1 + i);
  float acc[4] = {};
  for (int ch = 0; ch < 64; ++ch) {
    if (ch + 1 < 64) {
#pragma unroll
      for (int i = 0; i < 3; ++i) nxt[i] = ldrow(ch + 1, r0 - 1 + i);
    }
    float lf[3], rg[3];
#pragma unroll
    for (int i = 0; i < 3; ++i) {
      lf[i] = __shfl_up(cur[i], 1, 64);   if (px == 0)  lf[i] = 0.f;
      rg[i] = __shfl_down(cur[i], 1, 64); if (px == 63) rg[i] = 0.f;
    }
#pragma unroll
    for (int ky = 0; ky < 3; ++ky) {
      float4 w0 = wl4[ch * 9 + ky * 3 + 0];
      float4 w1 = wl4[ch * 9 + ky * 3 + 1];
      float4 w2 = wl4[ch * 9 + ky * 3 + 2];
      acc[0] = fmaf(w0.x, lf[ky], fmaf(w1.x, cur[ky], fmaf(w2.x, rg[ky], acc[0])));
      acc[1] = fmaf(w0.y, lf[ky], fmaf(w1.y, cur[ky], fmaf(w2.y, rg[ky], acc[1])));
      acc[2] = fmaf(w0.z, lf[ky], fmaf(w1.z, cur[ky], fmaf(w2.z, rg[ky], acc[2])));
      acc[3] = fmaf(w0.w, lf[ky], fmaf(w1.w, cur[ky], fmaf(w2.w, rg[ky], acc[3])));
    }
#pragma unroll
    for (int i = 0; i < 3; ++i) cur[i] = nxt[i];
  }
  float4 bb = *reinterpret_cast<const float4*>(&c1b[o0]);
  float* ub = ws + UB_OFF + (size_t)b * CN;
  size_t pix = (size_t)r0 * 64 + px;
  ub[(size_t)(o0 + 0) * N_ + pix] = leaky(acc[0] + bb.x);
  ub[(size_t)(o0 + 1) * N_ + pix] = leaky(acc[1] + bb.y);
  ub[(size_t)(o0 + 2) * N_ + pix] = leaky(acc[2] + bb.z);
  ub[(size_t)(o0 + 3) * N_ + pix] = leaky(acc[3] + bb.w);
}

// ---------------- K6: final, barrier-free, wave = 1 row, 4 oc + fused sc dot ----------------
__global__ __launch_bounds__(128) void k_final(const float* __restrict__ ws,
                                               const float* __restrict__ c2w,
                                               const float* __restrict__ c2b,
                                               const float* __restrict__ scw,
                                               const float* __restrict__ scb,
                                               float* __restrict__ out) {
  int blk = blockIdx.x;  // 1024 = b*512 + og*32 + rt
  int rt = blk & 31; blk >>= 5;
  int og = blk & 15; blk >>= 4;
  int b  = blk;
  int o0 = og * 4;
  __shared__ __align__(16) float4 wl4[576];
  __shared__ __align__(16) float4 scl4[64];
  int t = threadIdx.x;
  int wv = t >> 6, px = t & 63;
  {
    float* wlf = (float*)wl4;
    for (int idx = t; idx < 2304; idx += 128)
      wlf[idx] = c2w[(size_t)(o0 + (idx & 3)) * 576 + (idx >> 2)];
    float* sclf = (float*)scl4;
    for (int idx = t; idx < 256; idx += 128)
      sclf[idx] = scw[(size_t)(o0 + (idx & 3)) * 64 + (idx >> 2)];
  }
  __syncthreads();

  const float* u0 = ws + UB_OFF + (size_t)b * CN;
  const float* ob0 = ws + OB_OFF + (size_t)b * CN;
  int r0 = rt * 2 + wv;
  size_t pix = (size_t)r0 * 64 + px;
  auto ldrow = [&](int ch, int rr) -> float {
    if (rr < 0 || rr > 63) return 0.f;
    return u0[(size_t)ch * N_ + (size_t)rr * 64 + px];
  };
  float cur[3], nxt[3];
#pragma unroll
  for (int i = 0; i < 3; ++i) cur[i] = ldrow(0, r0 - 1 + i);
  float obc = ob0[pix], obn;
  float acc[4] = {};
  float scp[4] = {};
  for (int ch = 0; ch < 64; ++ch) {
    if (ch + 1 < 64) {
#pragma unroll
      for (int i = 0; i < 3; ++i) nxt[i] = ldrow(ch + 1, r0 - 1 + i);
      obn = ob0[(size_t)(ch + 1) * N_ + pix];
    }
    float lf[3], rg[3];
#pragma unroll
    for (int i = 0; i < 3; ++i) {
      lf[i] = __shfl_up(cur[i], 1, 64);   if (px == 0)  lf[i] = 0.f;
      rg[i] = __shfl_down(cur[i], 1, 64); if (px == 63) rg[i] = 0.f;
    }
#pragma unroll
    for (int ky = 0; ky < 3; ++ky) {
      float4 w0 = wl4[ch * 9 + ky * 3 + 0];
      float4 w1 = wl4[ch * 9 + ky * 3 + 1];
      float4 w2 = wl4[ch * 9 + ky * 3 + 2];
      acc[0] = fmaf(w0.x, lf[ky], fmaf(w1.x, cur[ky], fmaf(w2.x, rg[ky], acc[0])));
      acc[1] = fmaf(w0.y, lf[ky], fmaf(w1.y, cur[ky], fmaf(w2.y, rg[ky], acc[1])));
      acc[2] = fmaf(w0.z, lf[ky], fmaf(w1.z, cur[ky], fmaf(w2.z, rg[ky], acc[2])));
      acc[3] = fmaf(w0.w, lf[ky], fmaf(w1.w, cur[ky], fmaf(w2.w, rg[ky], acc[3])));
    }
    float4 s4 = scl4[ch];
    scp[0] = fmaf(s4.x, obc, scp[0]);
    scp[1] = fmaf(s4.y, obc, scp[1]);
    scp[2] = fmaf(s4.z, obc, scp[2]);
    scp[3] = fmaf(s4.w, obc, scp[3]);
#pragma unroll
    for (int i = 0; i < 3; ++i) cur[i] = nxt[i];
    obc = obn;
  }
  float4 c2bv = *reinterpret_cast<const float4*>(&c2b[o0]);
  float4 scbv = *reinterpret_cast<const float4*>(&scb[o0]);
  const float* go = ws + GO_OFF + (size_t)b * CN;
  float* ob = out + (size_t)b * CN;
  float cb[4] = {c2bv.x, c2bv.y, c2bv.z, c2bv.w};
  float sb[4] = {scbv.x, scbv.y, scbv.z, scbv.w};
#pragma unroll
  for (int oo = 0; oo < 4; ++oo) {
    float gvv = go[(size_t)(o0 + oo) * N_ + pix];
    ob[(size_t)(o0 + oo) * N_ + pix] = (acc[oo] + cb[oo]) + (scp[oo] + sb[oo]) * gvv;
  }
}

extern "C" void kernel_launch(void* const* d_in, const int* in_sizes, int n_in,
                              void* d_out, int out_size, void* d_ws, size_t ws_size,
                              hipStream_t stream) {
  const float* x     = (const float*)d_in[0];
  const float* guide = (const float*)d_in[1];
  const float* lin_w = (const float*)d_in[2];
  const float* lin_b = (const float*)d_in[3];
  const float* cw    = (const float*)d_in[4];
  const float* xq_w  = (const float*)d_in[5];
  const float* xq_b  = (const float*)d_in[6];
  const float* xk_w  = (const float*)d_in[7];
  const float* xk_b  = (const float*)d_in[8];
  const float* xv_w  = (const float*)d_in[9];
  const float* xv_b  = (const float*)d_in[10];
  const float* gq_w  = (const float*)d_in[11];
  const float* gq_b  = (const float*)d_in[12];
  const float* gk_w  = (const float*)d_in[13];
  const float* gk_b  = (const float*)d_in[14];
  const float* gamma = (const float*)d_in[15];
  const float* alpha = (const float*)d_in[16];
  const float* c1_w  = (const float*)d_in[17];
  const float* c1_b  = (const float*)d_in[18];
  const float* c2_w  = (const float*)d_in[19];
  const float* c2_b  = (const float*)d_in[20];
  const float* sc_w  = (const float*)d_in[21];
  const float* sc_b  = (const float*)d_in[22];
  float* out = (float*)d_out;
  float* ws = (float*)d_ws;

  k_coordconv<<<512, 256, 0, stream>>>(x, guide, lin_w, lin_b, cw, ws);
  k_proj<<<640, 256, 0, stream>>>(ws, xq_w, xq_b, xk_w, xk_b, xv_w, xv_b,
                                  gq_w, gq_b, gk_w, gk_b);
  k_attn<<<512, 256, 0, stream>>>(ws);
  k_merge<<<512, 256, 0, stream>>>(ws, gamma, alpha);
  k_conv1<<<1024, 128, 0, stream>>>(ws, c1_w, c1_b);
  k_final<<<1024, 128, 0, stream>>>(ws, c2_w, c2_b, sc_w, sc_b, out);
}

// Round 4
// 269.866 us; speedup vs baseline: 1.2592x; 1.2592x over previous
//
#include <hip/hip_runtime.h>
#include <hip/hip_bf16.h>

using bf16 = __hip_bfloat16;

#define DI __device__ __forceinline__

typedef __attribute__((ext_vector_type(8))) short short8;
typedef __attribute__((ext_vector_type(8))) unsigned short u16x8;
typedef __attribute__((ext_vector_type(4))) unsigned short u16x4;
typedef __attribute__((ext_vector_type(4))) float f32x4;

#define MFMA_BF16 __builtin_amdgcn_mfma_f32_16x16x32_bf16

DI float leaky(float x) { return x > 0.f ? x : 0.1f * x; }

// bf16 split helpers (RNE). x = hi + lo to ~2^-16 relative.
DI unsigned short b16(float x) {
  union { float f; unsigned u; } v; v.f = x;
  unsigned r = v.u + 0x7FFFu + ((v.u >> 16) & 1u);
  return (unsigned short)(r >> 16);
}
DI float fromb16(unsigned short h) {
  union { unsigned u; float f; } v; v.u = ((unsigned)h) << 16; return v.f;
}

// Problem constants: B=2, C=64, H=64, W=64, N=4096. Inputs fp32 (R3/R4).
// NOTE R13: hipLaunchCooperativeKernel fails silently under graph capture here.
// Precision ladder (validated): Q/K split bf16, P hi-only, V hi-only in PV,
// L via ones-row MFMA. R2: swapped QK^T -> lane owns one pixel.
// R4: convs channel-split. R3's barrier-free form was latency-bound (VALUBusy
// 12.7%, 2500 cyc stall/iter: 64-deep serial chain at 2 waves/SIMD reading
// cross-XCD dirty lines). Now: block = 1 row x 4 oc, 4 waves x 16 ch each,
// ALL 48 row-values loaded upfront (one vmcnt staircase), one LDS reduce.
// Chain 64 -> 16 iters, grid 2048-4096 (full occupancy). CA means -> k_ca
// (stored at ML_OFF; attn overwrites ML only after coordconv consumed it).
static constexpr int N_ = 4096;
static constexpr size_t CN = 262144;
static constexpr size_t BCN = 524288;

// ---- Workspace layout (float indices) ----
static constexpr size_t XG_OFF = 137104;
static constexpr size_t GG_OFF = XG_OFF + BCN;
static constexpr size_t QX_OFF = GG_OFF + BCN;
static constexpr size_t KX_OFF = QX_OFF + BCN;
static constexpr size_t VX_OFF = KX_OFF + BCN;
static constexpr size_t QG_OFF = VX_OFF + BCN;
static constexpr size_t KG_OFF = QG_OFF + BCN;
static constexpr size_t P1X_OFF = KG_OFF + BCN;
static constexpr size_t P1G_OFF = P1X_OFF + BCN;
static constexpr size_t ML_OFF  = P1G_OFF + BCN;
static constexpr size_t MLL_OFF = ML_OFF + 32768;
static constexpr size_t CA_OFF = ML_OFF;   // 256 floats; consumed by coordconv before attn writes ML
static constexpr size_t OB_OFF = QX_OFF;
static constexpr size_t UB_OFF = KX_OFF;
static constexpr size_t GO_OFF = GG_OFF;
static constexpr size_t QXH_U = QX_OFF * 2, QXL_U = QXH_U + BCN;
static constexpr size_t KXH_U = KX_OFF * 2, KXL_U = KXH_U + BCN;
static constexpr size_t VXH_U = VX_OFF * 2;
static constexpr size_t QGH_U = QG_OFF * 2, QGL_U = QGH_U + BCN;
static constexpr size_t KGH_U = KG_OFF * 2, KGL_U = KGH_U + BCN;
// Peak 19.7 MB (validated R6-R14)

// ---------------- K0: channel-attention scales (256 = src*128 + b*64 + ch) ----------------
__global__ __launch_bounds__(64) void k_ca(const float* __restrict__ x,
                                           const float* __restrict__ g,
                                           const float* __restrict__ lw_p,
                                           const float* __restrict__ lb_p,
                                           float* __restrict__ ws) {
  int blk = blockIdx.x;
  int ch = blk & 63; blk >>= 6;
  int b  = blk & 1;  blk >>= 1;
  int src = blk;
  const float* in = (src ? g : x) + ((size_t)(b * 64 + ch)) * N_;
  int t = threadIdx.x;
  float s = 0.f;
#pragma unroll
  for (int i = 0; i < 16; ++i) {
    float4 v = *reinterpret_cast<const float4*>(in + i * 256 + t * 4);
    s += (v.x + v.y) + (v.z + v.w);
  }
#pragma unroll
  for (int d = 1; d < 64; d <<= 1) s += __shfl_xor(s, d, 64);
  if (t == 0) {
    float p = s * (1.f / 4096.f);
    float lwv = lw_p[0], lbv = lb_p[0];
    float h = leaky(lwv * p + lbv);
    ws[CA_OFF + (src * 2 + b) * 64 + ch] = 1.f / (1.f + expf(-(lwv * h + lbv)));
  }
}

// ---------------- K1: coord-conv 3x3, channel-split (1 row x 4 oc / block) ----------------
__global__ __launch_bounds__(256) void k_coordconv(const float* __restrict__ x,
                                                   const float* __restrict__ g,
                                                   const float* __restrict__ cw,
                                                   float* __restrict__ ws) {
  int blk = blockIdx.x;  // 4096 = src*2048 + b*1024 + og*64 + row
  int row = blk & 63; blk >>= 6;
  int og  = blk & 15; blk >>= 4;
  int b   = blk & 1;  blk >>= 1;
  int src = blk;
  int o0 = og * 4;
  const float* in = src ? g : x;
  float* outp = ws + (src ? GG_OFF : XG_OFF);
  __shared__ __align__(16) float4 wl4[594];   // [ch*9+tap] -> 4 oc
  __shared__ float part[4][4][64];
  int t = threadIdx.x;
  int wv = t >> 6, px = t & 63;
  {
    float* wlf = (float*)wl4;
    for (int idx = t; idx < 2376; idx += 256)
      wlf[idx] = cw[(size_t)(o0 + (idx & 3)) * 594 + (idx >> 2)];
  }
  int rm = row - 1, rp = row + 1;
  int rmc = rm < 0 ? 0 : rm, rpc = rp > 63 ? 63 : rp;
  float maskm = rm < 0 ? 0.f : 1.f, maskp = rp > 63 ? 0.f : 1.f;
  int c0 = wv * 16;
  const float* base = in + ((size_t)(b * 64 + c0)) * N_ + px;
  float ra[16], rb[16], rc[16];
#pragma unroll
  for (int i = 0; i < 16; ++i) {
    ra[i] = base[(size_t)i * N_ + (size_t)rmc * 64] * maskm;
    rb[i] = base[(size_t)i * N_ + (size_t)row * 64];
    rc[i] = base[(size_t)i * N_ + (size_t)rpc * 64] * maskp;
  }
  float acc[4] = {};
  auto tap9 = [&](int ch, float va, float vb, float vc) {
    float la = __shfl_up(va, 1, 64);   if (px == 0)  la = 0.f;
    float ga = __shfl_down(va, 1, 64); if (px == 63) ga = 0.f;
    float lb = __shfl_up(vb, 1, 64);   if (px == 0)  lb = 0.f;
    float gb = __shfl_down(vb, 1, 64); if (px == 63) gb = 0.f;
    float lc = __shfl_up(vc, 1, 64);   if (px == 0)  lc = 0.f;
    float gc = __shfl_down(vc, 1, 64); if (px == 63) gc = 0.f;
    float4 w0 = wl4[ch * 9 + 0], w1 = wl4[ch * 9 + 1], w2 = wl4[ch * 9 + 2];
    float4 w3 = wl4[ch * 9 + 3], w4 = wl4[ch * 9 + 4], w5 = wl4[ch * 9 + 5];
    float4 w6 = wl4[ch * 9 + 6], w7 = wl4[ch * 9 + 7], w8 = wl4[ch * 9 + 8];
    acc[0] = fmaf(w0.x, la, fmaf(w1.x, va, fmaf(w2.x, ga, acc[0])));
    acc[1] = fmaf(w0.y, la, fmaf(w1.y, va, fmaf(w2.y, ga, acc[1])));
    acc[2] = fmaf(w0.z, la, fmaf(w1.z, va, fmaf(w2.z, ga, acc[2])));
    acc[3] = fmaf(w0.w, la, fmaf(w1.w, va, fmaf(w2.w, ga, acc[3])));
    acc[0] = fmaf(w3.x, lb, fmaf(w4.x, vb, fmaf(w5.x, gb, acc[0])));
    acc[1] = fmaf(w3.y, lb, fmaf(w4.y, vb, fmaf(w5.y, gb, acc[1])));
    acc[2] = fmaf(w3.z, lb, fmaf(w4.z, vb, fmaf(w5.z, gb, acc[2])));
    acc[3] = fmaf(w3.w, lb, fmaf(w4.w, vb, fmaf(w5.w, gb, acc[3])));
    acc[0] = fmaf(w6.x, lc, fmaf(w7.x, vc, fmaf(w8.x, gc, acc[0])));
    acc[1] = fmaf(w6.y, lc, fmaf(w7.y, vc, fmaf(w8.y, gc, acc[1])));
    acc[2] = fmaf(w6.z, lc, fmaf(w7.z, vc, fmaf(w8.z, gc, acc[2])));
    acc[3] = fmaf(w6.w, lc, fmaf(w7.w, vc, fmaf(w8.w, gc, acc[3])));
  };
  __syncthreads();   // weights ready
#pragma unroll
  for (int i = 0; i < 16; ++i) tap9(c0 + i, ra[i], rb[i], rc[i]);
  if (wv == 3) {
    // ch 64: xx varies along px (zero-padded rows/cols like real channels)
    float xx = (float)px * (2.f / 63.f) - 1.f;
    tap9(64, maskm * xx, xx, maskp * xx);
    // ch 65: yy constant along px, varies by row
    float ya = maskm * ((float)rm * (2.f / 63.f) - 1.f);
    float yb = (float)row * (2.f / 63.f) - 1.f;
    float yc = maskp * ((float)rp * (2.f / 63.f) - 1.f);
    tap9(65, ya, yb, yc);
  }
#pragma unroll
  for (int oo = 0; oo < 4; ++oo) part[wv][oo][px] = acc[oo];
  __syncthreads();
  int oc = t >> 6;
  float s = (part[0][oc][px] + part[1][oc][px]) + (part[2][oc][px] + part[3][oc][px]);
  float cav = ws[CA_OFF + (src * 2 + b) * 64 + o0 + oc];
  outp[((size_t)(b * 64 + o0 + oc)) * N_ + (size_t)row * 64 + px] = s * cav;
}

// ---------------- K2: 1x1 projections; Q/K pre-split hi/lo, V hi-only transposed ----------------
__global__ __launch_bounds__(256) void k_proj(float* __restrict__ ws,
                                              const float* __restrict__ xqw, const float* __restrict__ xqb,
                                              const float* __restrict__ xkw, const float* __restrict__ xkb,
                                              const float* __restrict__ xvw, const float* __restrict__ xvb,
                                              const float* __restrict__ gqw, const float* __restrict__ gqb,
                                              const float* __restrict__ gkw, const float* __restrict__ gkb) {
  int blk = blockIdx.x;  // 5 * 2 * 64
  int pt = blk & 63; blk >>= 6;
  int b  = blk & 1;  blk >>= 1;
  int which = blk;
  size_t in_o;
  const float *wp, *bp;
  size_t hU = 0, lU = 0;
  if (which == 0)      { in_o = XG_OFF; wp = xqw; bp = xqb; hU = QXH_U; lU = QXL_U; }
  else if (which == 1) { in_o = XG_OFF; wp = xkw; bp = xkb; hU = KXH_U; lU = KXL_U; }
  else if (which == 2) { in_o = XG_OFF; wp = xvw; bp = xvb; }
  else if (which == 3) { in_o = GG_OFF; wp = gqw; bp = gqb; hU = QGH_U; lU = QGL_U; }
  else                 { in_o = GG_OFF; wp = gkw; bp = gkb; hU = KGH_U; lU = KGL_U; }

  __shared__ float tile[64 * 64];
  __shared__ float wl[64 * 65];
  __shared__ float bl[64];
  unsigned short* us = (unsigned short*)ws;
  int t = threadIdx.x;
  int pb = pt * 64;
  const float* in0 = ws + in_o + (size_t)b * CN + pb;
  for (int c0 = (t >> 6); c0 < 64; c0 += 4)
    tile[c0 * 64 + (t & 63)] = in0[(size_t)c0 * N_ + (t & 63)];
  for (int idx = t; idx < 4096; idx += 256)
    wl[(idx >> 6) * 65 + (idx & 63)] = wp[idx];
  if (t < 64) bl[t] = bp[t];
  __syncthreads();
  int o = t & 63, grp = t >> 6;
  const float* wr = &wl[o * 65];
  float acc[16];
  float bv = bl[o];
#pragma unroll
  for (int j = 0; j < 16; ++j) acc[j] = bv;
  for (int c = 0; c < 64; ++c) {
    float wv = wr[c];
    const float4* tb = reinterpret_cast<const float4*>(&tile[c * 64 + grp * 16]);
    float4 t0 = tb[0], t1 = tb[1], t2 = tb[2], t3 = tb[3];
    acc[0] = fmaf(wv, t0.x, acc[0]);   acc[1] = fmaf(wv, t0.y, acc[1]);
    acc[2] = fmaf(wv, t0.z, acc[2]);   acc[3] = fmaf(wv, t0.w, acc[3]);
    acc[4] = fmaf(wv, t1.x, acc[4]);   acc[5] = fmaf(wv, t1.y, acc[5]);
    acc[6] = fmaf(wv, t1.z, acc[6]);   acc[7] = fmaf(wv, t1.w, acc[7]);
    acc[8] = fmaf(wv, t2.x, acc[8]);   acc[9] = fmaf(wv, t2.y, acc[9]);
    acc[10] = fmaf(wv, t2.z, acc[10]); acc[11] = fmaf(wv, t2.w, acc[11]);
    acc[12] = fmaf(wv, t3.x, acc[12]); acc[13] = fmaf(wv, t3.y, acc[13]);
    acc[14] = fmaf(wv, t3.z, acc[14]); acc[15] = fmaf(wv, t3.w, acc[15]);
  }
  if (which != 2) {
#pragma unroll
    for (int j = 0; j < 16; ++j) {
      size_t idx = ((size_t)b * N_ + pb + grp * 16 + j) * 64 + o;
      unsigned short hi = b16(acc[j]);
      us[hU + idx] = hi;
      us[lU + idx] = b16(acc[j] - fromb16(hi));
    }
  } else {
    __syncthreads();
    float* ot = wl;
#pragma unroll
    for (int j = 0; j < 16; ++j) ot[o * 65 + grp * 16 + j] = acc[j];
    __syncthreads();
    int o2 = t >> 2;
#pragma unroll
    for (int e = 0; e < 4; ++e) {
      int px = (t & 3) * 16 + e * 4;
      u16x4 hv;
#pragma unroll
      for (int q = 0; q < 4; ++q) hv[q] = b16(ot[o2 * 65 + px + q]);
      size_t idx = ((size_t)(b * 64 + o2)) * N_ + pb + px;
      *reinterpret_cast<u16x4*>(&us[VXH_U + idx]) = hv;
    }
  }
}

// ---------------- K3: MFMA flash attention (swapped QK^T: lane owns one pixel) ----------------
__global__ __launch_bounds__(256) void k_attn(float* __restrict__ ws) {
  unsigned short* us = (unsigned short*)ws;
  int blk = blockIdx.x;
  int half = blk & 1; blk >>= 1;
  int qt = blk & 63;  blk >>= 6;
  int b  = blk & 1;   blk >>= 1;
  int at = blk;
  const unsigned short* QH = us + (at ? QGH_U : QXH_U);
  const unsigned short* QL = us + (at ? QGL_U : QXL_U);
  const unsigned short* KHg = us + (at ? KGH_U : KXH_U);
  const unsigned short* KLg = us + (at ? KGL_U : KXL_U);
  const unsigned short* VHg = us + VXH_U;
  float* Pg = ws + (at ? (half ? P1G_OFF : GG_OFF) : (half ? P1X_OFF : XG_OFF))
            + (size_t)b * CN + qt * 64;

  __shared__ unsigned short Kh[2][4096], Kl[2][4096], Vth[2][4096], Ph[4096];

  int t = threadIdx.x;
  int w = t >> 6, lane = t & 63, quad = lane >> 4, l15 = lane & 15;
  int swz = l15 & 7;

  short8 qh[2], ql[2];
  {
    size_t qbase = ((size_t)b * N_ + qt * 64 + 16 * w + l15) * 64;
#pragma unroll
    for (int ks = 0; ks < 2; ++ks) {
      qh[ks] = *reinterpret_cast<const short8*>(&QH[qbase + ks * 32 + quad * 8]);
      ql[ks] = *reinterpret_cast<const short8*>(&QL[qbase + ks * 32 + quad * 8]);
    }
  }

  short8 ones;
#pragma unroll
  for (int j = 0; j < 8; ++j) ones[j] = (short)0x3F80;  // bf16 1.0

  int mt0 = half * 32, mt1 = half * 32 + 32;

  u16x8 rkh[2], rkl[2], rvh[2];
  size_t ko = ((size_t)b * N_ + (size_t)mt0 * 64 + (t >> 3)) * 64 + (size_t)(t & 7) * 8;
  size_t vo = ((size_t)(b * 64) + (t >> 3)) * N_ + (size_t)mt0 * 64 + (size_t)(t & 7) * 8;
  auto prefetch = [&]() {
    rkh[0] = *reinterpret_cast<const u16x8*>(&KHg[ko]);
    rkl[0] = *reinterpret_cast<const u16x8*>(&KLg[ko]);
    rkh[1] = *reinterpret_cast<const u16x8*>(&KHg[ko + 2048]);
    rkl[1] = *reinterpret_cast<const u16x8*>(&KLg[ko + 2048]);
    rvh[0] = *reinterpret_cast<const u16x8*>(&VHg[vo]);
    rvh[1] = *reinterpret_cast<const u16x8*>(&VHg[vo + (size_t)32 * N_]);
    ko += 4096; vo += 64;
  };
  int wr0 = t >> 3, wch = t & 7;
  int woff = wr0 * 64 + ((wch ^ (wr0 & 7)) << 3);
  auto writebuf = [&](int par) {
    *reinterpret_cast<u16x8*>(&Kh[par][woff]) = rkh[0];
    *reinterpret_cast<u16x8*>(&Kl[par][woff]) = rkl[0];
    *reinterpret_cast<u16x8*>(&Vth[par][woff]) = rvh[0];
    *reinterpret_cast<u16x8*>(&Kh[par][woff + 2048]) = rkh[1];
    *reinterpret_cast<u16x8*>(&Kl[par][woff + 2048]) = rkl[1];
    *reinterpret_cast<u16x8*>(&Vth[par][woff + 2048]) = rvh[1];
  };

  f32x4 Oa[4] = {{0.f, 0.f, 0.f, 0.f}, {0.f, 0.f, 0.f, 0.f},
                 {0.f, 0.f, 0.f, 0.f}, {0.f, 0.f, 0.f, 0.f}};
  f32x4 La = {0.f, 0.f, 0.f, 0.f};   // L in element 0 (ones-row MFMA; rows identical)
  float M = -1e30f;                  // per-lane: pixel n = 16w + l15

  int phb = (16 * w + l15) * 64;
  int mh = quad >> 1, mlw = (quad & 1) * 4;

  prefetch();
  writebuf(0);
  __syncthreads();
  for (int mt = mt0; mt < mt1; ++mt) {
    int pb = (mt - mt0) & 1;
    if (mt + 1 < mt1) prefetch();  // global latency overlaps tile compute

    // S^T[m][n]: m = ms*16 + quad*4 + reg, n = 16w + l15 (swapped operands)
    f32x4 S[4];
    __builtin_amdgcn_s_setprio(1);
#pragma unroll
    for (int ms = 0; ms < 4; ++ms) {
      f32x4 a0 = {0.f, 0.f, 0.f, 0.f}, a1 = {0.f, 0.f, 0.f, 0.f};
      int row = ms * 16 + l15;
#pragma unroll
      for (int ks = 0; ks < 2; ++ks) {
        int off = row * 64 + (((ks * 4 + quad) ^ swz) << 3);
        short8 khf = *reinterpret_cast<const short8*>(&Kh[pb][off]);
        short8 klf = *reinterpret_cast<const short8*>(&Kl[pb][off]);
        f32x4& a = ks ? a1 : a0;
        a = MFMA_BF16(khf, ql[ks], a, 0, 0, 0);
        a = MFMA_BF16(klf, qh[ks], a, 0, 0, 0);
        a = MFMA_BF16(khf, qh[ks], a, 0, 0, 0);
      }
      S[ms] = a0 + a1;
    }
    __builtin_amdgcn_s_setprio(0);

    // in-lane max over 16 values + 2-step cross-quad butterfly
    float m0 = fmaxf(fmaxf(S[0][0], S[0][1]), fmaxf(S[0][2], S[0][3]));
    float m1 = fmaxf(fmaxf(S[1][0], S[1][1]), fmaxf(S[1][2], S[1][3]));
    float m2 = fmaxf(fmaxf(S[2][0], S[2][1]), fmaxf(S[2][2], S[2][3]));
    float m3 = fmaxf(fmaxf(S[3][0], S[3][1]), fmaxf(S[3][2], S[3][3]));
    float tm = fmaxf(fmaxf(m0, m1), fmaxf(m2, m3));
    tm = fmaxf(tm, __shfl_xor(tm, 16, 64));
    tm = fmaxf(tm, __shfl_xor(tm, 32, 64));
    float mn = fmaxf(M, tm);
    float al = __expf(M - mn);
    M = mn;
#pragma unroll
    for (int ms = 0; ms < 4; ++ms) {
      int goff = phb + ((((ms << 1) + mh) ^ swz) << 3) + mlw;
#pragma unroll
      for (int r = 0; r < 4; ++r) {
        float p = __expf(S[ms][r] - mn);
        Ph[goff + r] = b16(p);   // wave-private rows -> no barrier needed
      }
    }
#pragma unroll
    for (int cs = 0; cs < 4; ++cs) {
      Oa[cs][0] *= al; Oa[cs][1] *= al; Oa[cs][2] *= al; Oa[cs][3] *= al;
    }
    La[0] *= al;

    // O^T += V^T P^T, V hi-only: 10 MFMAs (incl. 2 ones-row for L), 10 ds_reads/tile
    __builtin_amdgcn_s_setprio(1);
#pragma unroll
    for (int ks = 0; ks < 2; ++ks) {
      int poff = phb + (((ks * 4 + quad) ^ swz) << 3);
      short8 phf = *reinterpret_cast<const short8*>(&Ph[poff]);
      La = MFMA_BF16(ones, phf, La, 0, 0, 0);   // row-sums of P == L partials
#pragma unroll
      for (int cs = 0; cs < 4; ++cs) {
        int voff = (cs * 16 + l15) * 64 + (((ks * 4 + quad) ^ swz) << 3);
        short8 vhf = *reinterpret_cast<const short8*>(&Vth[pb][voff]);
        Oa[cs] = MFMA_BF16(vhf, phf, Oa[cs], 0, 0, 0);
      }
    }
    __builtin_amdgcn_s_setprio(0);

    if (mt + 1 < mt1) writebuf(pb ^ 1);  // fenced by previous iteration's barrier
    __syncthreads();
  }

#pragma unroll
  for (int cs = 0; cs < 4; ++cs) {
#pragma unroll
    for (int r = 0; r < 4; ++r) {
      int c = cs * 16 + quad * 4 + r;
      Pg[(size_t)c * N_ + 16 * w + l15] = Oa[cs][r];
    }
  }
  if (quad == 0) {
    int mlb = ((at * 2 + half) * 2 + b) * 4096 + qt * 64 + 16 * w + l15;
    ws[ML_OFF + mlb] = M;
    ws[MLL_OFF + mlb] = La[0];   // La col = pixel 16w+l15, rows identical
  }
}

// ---------------- K4: merge halves + combine ----------------
__global__ __launch_bounds__(256) void k_merge(float* __restrict__ ws,
                                               const float* __restrict__ gm_p,
                                               const float* __restrict__ al_p) {
  size_t i4 = (size_t)blockIdx.x * 256 + threadIdx.x;
  size_t i = i4 * 4;
  int n = (int)(i & 4095);
  int b = (int)(i >> 18);
  float gm = gm_p[0], al = al_p[0];
  float4 p0x = *reinterpret_cast<const float4*>(ws + XG_OFF + i);
  float4 p1x = *reinterpret_cast<const float4*>(ws + P1X_OFF + i);
  float4 p0g = *reinterpret_cast<const float4*>(ws + GG_OFF + i);
  float4 p1g = *reinterpret_cast<const float4*>(ws + P1G_OFF + i);
  float4 M0x = *reinterpret_cast<const float4*>(ws + ML_OFF  + (0 + b) * 4096 + n);
  float4 L0x = *reinterpret_cast<const float4*>(ws + MLL_OFF + (0 + b) * 4096 + n);
  float4 M1x = *reinterpret_cast<const float4*>(ws + ML_OFF  + (2 + b) * 4096 + n);
  float4 L1x = *reinterpret_cast<const float4*>(ws + MLL_OFF + (2 + b) * 4096 + n);
  float4 M0g = *reinterpret_cast<const float4*>(ws + ML_OFF  + (4 + b) * 4096 + n);
  float4 L0g = *reinterpret_cast<const float4*>(ws + MLL_OFF + (4 + b) * 4096 + n);
  float4 M1g = *reinterpret_cast<const float4*>(ws + ML_OFF  + (6 + b) * 4096 + n);
  float4 L1g = *reinterpret_cast<const float4*>(ws + MLL_OFF + (6 + b) * 4096 + n);
  const float* p0xv = (const float*)&p0x; const float* p1xv = (const float*)&p1x;
  const float* p0gv = (const float*)&p0g; const float* p1gv = (const float*)&p1g;
  const float* m0xv = (const float*)&M0x; const float* l0xv = (const float*)&L0x;
  const float* m1xv = (const float*)&M1x; const float* l1xv = (const float*)&L1x;
  const float* m0gv = (const float*)&M0g; const float* l0gv = (const float*)&L0g;
  const float* m1gv = (const float*)&M1g; const float* l1gv = (const float*)&L1g;
  float4 go, ob;
  float* gov = (float*)&go; float* obv = (float*)&ob;
#pragma unroll
  for (int l = 0; l < 4; ++l) {
    float mx = fmaxf(m0xv[l], m1xv[l]);
    float w0 = __expf(m0xv[l] - mx), w1 = __expf(m1xv[l] - mx);
    float xc = (p0xv[l] * w0 + p1xv[l] * w1) / (l0xv[l] * w0 + l1xv[l] * w1);
    float mg = fmaxf(m0gv[l], m1gv[l]);
    float v0 = __expf(m0gv[l] - mg), v1 = __expf(m1gv[l] - mg);
    float gc = (p0gv[l] * v0 + p1gv[l] * v1) / (l0gv[l] * v0 + l1gv[l] * v1);
    gov[l] = gc;
    obv[l] = gm * xc + al * gc;
  }
  *reinterpret_cast<float4*>(ws + GG_OFF + i) = go;  // GO
  *reinterpret_cast<float4*>(ws + QX_OFF + i) = ob;  // OB
}

// ---------------- K5: u = leaky(conv3x3(leaky(out), c1)), channel-split ----------------
__global__ __launch_bounds__(256) void k_conv1(float* __restrict__ ws,
                                               const float* __restrict__ c1w,
                                               const float* __restrict__ c1b) {
  int blk = blockIdx.x;  // 2048 = b*1024 + og*64 + row
  int row = blk & 63; blk >>= 6;
  int og  = blk & 15; blk >>= 4;
  int b   = blk;
  int o0 = og * 4;
  __shared__ __align__(16) float4 wl4[576];
  __shared__ float part[4][4][64];
  int t = threadIdx.x;
  int wv = t >> 6, px = t & 63;
  {
    float* wlf = (float*)wl4;
    for (int idx = t; idx < 2304; idx += 256)
      wlf[idx] = c1w[(size_t)(o0 + (idx & 3)) * 576 + (idx >> 2)];
  }
  int rm = row - 1, rp = row + 1;
  int rmc = rm < 0 ? 0 : rm, rpc = rp > 63 ? 63 : rp;
  float maskm = rm < 0 ? 0.f : 1.f, maskp = rp > 63 ? 0.f : 1.f;
  int c0 = wv * 16;
  const float* base = ws + OB_OFF + (size_t)b * CN + (size_t)c0 * N_ + px;
  float ra[16], rb[16], rc[16];
#pragma unroll
  for (int i = 0; i < 16; ++i) {
    ra[i] = leaky(base[(size_t)i * N_ + (size_t)rmc * 64]) * maskm;
    rb[i] = leaky(base[(size_t)i * N_ + (size_t)row * 64]);
    rc[i] = leaky(base[(size_t)i * N_ + (size_t)rpc * 64]) * maskp;
  }
  float acc[4] = {};
  auto tap9 = [&](int ch, float va, float vb, float vc) {
    float la = __shfl_up(va, 1, 64);   if (px == 0)  la = 0.f;
    float ga = __shfl_down(va, 1, 64); if (px == 63) ga = 0.f;
    float lb = __shfl_up(vb, 1, 64);   if (px == 0)  lb = 0.f;
    float gb = __shfl_down(vb, 1, 64); if (px == 63) gb = 0.f;
    float lc = __shfl_up(vc, 1, 64);   if (px == 0)  lc = 0.f;
    float gc = __shfl_down(vc, 1, 64); if (px == 63) gc = 0.f;
    float4 w0 = wl4[ch * 9 + 0], w1 = wl4[ch * 9 + 1], w2 = wl4[ch * 9 + 2];
    float4 w3 = wl4[ch * 9 + 3], w4 = wl4[ch * 9 + 4], w5 = wl4[ch * 9 + 5];
    float4 w6 = wl4[ch * 9 + 6], w7 = wl4[ch * 9 + 7], w8 = wl4[ch * 9 + 8];
    acc[0] = fmaf(w0.x, la, fmaf(w1.x, va, fmaf(w2.x, ga, acc[0])));
    acc[1] = fmaf(w0.y, la, fmaf(w1.y, va, fmaf(w2.y, ga, acc[1])));
    acc[2] = fmaf(w0.z, la, fmaf(w1.z, va, fmaf(w2.z, ga, acc[2])));
    acc[3] = fmaf(w0.w, la, fmaf(w1.w, va, fmaf(w2.w, ga, acc[3])));
    acc[0] = fmaf(w3.x, lb, fmaf(w4.x, vb, fmaf(w5.x, gb, acc[0])));
    acc[1] = fmaf(w3.y, lb, fmaf(w4.y, vb, fmaf(w5.y, gb, acc[1])));
    acc[2] = fmaf(w3.z, lb, fmaf(w4.z, vb, fmaf(w5.z, gb, acc[2])));
    acc[3] = fmaf(w3.w, lb, fmaf(w4.w, vb, fmaf(w5.w, gb, acc[3])));
    acc[0] = fmaf(w6.x, lc, fmaf(w7.x, vc, fmaf(w8.x, gc, acc[0])));
    acc[1] = fmaf(w6.y, lc, fmaf(w7.y, vc, fmaf(w8.y, gc, acc[1])));
    acc[2] = fmaf(w6.z, lc, fmaf(w7.z, vc, fmaf(w8.z, gc, acc[2])));
    acc[3] = fmaf(w6.w, lc, fmaf(w7.w, vc, fmaf(w8.w, gc, acc[3])));
  };
  __syncthreads();
#pragma unroll
  for (int i = 0; i < 16; ++i) tap9(c0 + i, ra[i], rb[i], rc[i]);
#pragma unroll
  for (int oo = 0; oo < 4; ++oo) part[wv][oo][px] = acc[oo];
  __syncthreads();
  int oc = t >> 6;
  float s = (part[0][oc][px] + part[1][oc][px]) + (part[2][oc][px] + part[3][oc][px]);
  float* ub = ws + UB_OFF + (size_t)b * CN;
  ub[(size_t)(o0 + oc) * N_ + (size_t)row * 64 + px] = leaky(s + c1b[o0 + oc]);
}

// ---------------- K6: final, channel-split + fused sc dot ----------------
__global__ __launch_bounds__(256) void k_final(const float* __restrict__ ws,
                                               const float* __restrict__ c2w,
                                               const float* __restrict__ c2b,
                                               const float* __restrict__ scw,
                                               const float* __restrict__ scb,
                                               float* __restrict__ out) {
  int blk = blockIdx.x;  // 2048 = b*1024 + og*64 + row
  int row = blk & 63; blk >>= 6;
  int og  = blk & 15; blk >>= 4;
  int b   = blk;
  int o0 = og * 4;
  __shared__ __align__(16) float4 wl4[576];
  __shared__ __align__(16) float4 scl4[64];
  __shared__ float part[4][4][64];
  __shared__ float part2[4][4][64];
  int t = threadIdx.x;
  int wv = t >> 6, px = t & 63;
  {
    float* wlf = (float*)wl4;
    for (int idx = t; idx < 2304; idx += 256)
      wlf[idx] = c2w[(size_t)(o0 + (idx & 3)) * 576 + (idx >> 2)];
    float* sclf = (float*)scl4;
    if (t < 256) {
      int idx = t;
      sclf[idx] = scw[(size_t)(o0 + (idx & 3)) * 64 + (idx >> 2)];
    }
  }
  int rm = row - 1, rp = row + 1;
  int rmc = rm < 0 ? 0 : rm, rpc = rp > 63 ? 63 : rp;
  float maskm = rm < 0 ? 0.f : 1.f, maskp = rp > 63 ? 0.f : 1.f;
  int c0 = wv * 16;
  const float* base = ws + UB_OFF + (size_t)b * CN + (size_t)c0 * N_ + px;
  const float* obb  = ws + OB_OFF + (size_t)b * CN + (size_t)c0 * N_ + (size_t)row * 64 + px;
  float ra[16], rb[16], rc[16], ob[16];
#pragma unroll
  for (int i = 0; i < 16; ++i) {
    ra[i] = base[(size_t)i * N_ + (size_t)rmc * 64] * maskm;
    rb[i] = base[(size_t)i * N_ + (size_t)row * 64];
    rc[i] = base[(size_t)i * N_ + (size_t)rpc * 64] * maskp;
    ob[i] = obb[(size_t)i * N_];
  }
  float acc[4] = {};
  float scp[4] = {};
  auto tap9 = [&](int ch, float va, float vb, float vc) {
    float la = __shfl_up(va, 1, 64);   if (px == 0)  la = 0.f;
    float ga = __shfl_down(va, 1, 64); if (px == 63) ga = 0.f;
    float lb = __shfl_up(vb, 1, 64);   if (px == 0)  lb = 0.f;
    float gb = __shfl_down(vb, 1, 64); if (px == 63) gb = 0.f;
    float lc = __shfl_up(vc, 1, 64);   if (px == 0)  lc = 0.f;
    float gc = __shfl_down(vc, 1, 64); if (px == 63) gc = 0.f;
    float4 w0 = wl4[ch * 9 + 0], w1 = wl4[ch * 9 + 1], w2 = wl4[ch * 9 + 2];
    float4 w3 = wl4[ch * 9 + 3], w4 = wl4[ch * 9 + 4], w5 = wl4[ch * 9 + 5];
    float4 w6 = wl4[ch * 9 + 6], w7 = wl4[ch * 9 + 7], w8 = wl4[ch * 9 + 8];
    acc[0] = fmaf(w0.x, la, fmaf(w1.x, va, fmaf(w2.x, ga, acc[0])));
    acc[1] = fmaf(w0.y, la, fmaf(w1.y, va, fmaf(w2.y, ga, acc[1])));
    acc[2] = fmaf(w0.z, la, fmaf(w1.z, va, fmaf(w2.z, ga, acc[2])));
    acc[3] = fmaf(w0.w, la, fmaf(w1.w, va, fmaf(w2.w, ga, acc[3])));
    acc[0] = fmaf(w3.x, lb, fmaf(w4.x, vb, fmaf(w5.x, gb, acc[0])));
    acc[1] = fmaf(w3.y, lb, fmaf(w4.y, vb, fmaf(w5.y, gb, acc[1])));
    acc[2] = fmaf(w3.z, lb, fmaf(w4.z, vb, fmaf(w5.z, gb, acc[2])));
    acc[3] = fmaf(w3.w, lb, fmaf(w4.w, vb, fmaf(w5.w, gb, acc[3])));
    acc[0] = fmaf(w6.x, lc, fmaf(w7.x, vc, fmaf(w8.x, gc, acc[0])));
    acc[1] = fmaf(w6.y, lc, fmaf(w7.y, vc, fmaf(w8.y, gc, acc[1])));
    acc[2] = fmaf(w6.z, lc, fmaf(w7.z, vc, fmaf(w8.z, gc, acc[2])));
    acc[3] = fmaf(w6.w, lc, fmaf(w7.w, vc, fmaf(w8.w, gc, acc[3])));
  };
  __syncthreads();
#pragma unroll
  for (int i = 0; i < 16; ++i) {
    tap9(c0 + i, ra[i], rb[i], rc[i]);
    float4 s4 = scl4[c0 + i];
    scp[0] = fmaf(s4.x, ob[i], scp[0]);
    scp[1] = fmaf(s4.y, ob[i], scp[1]);
    scp[2] = fmaf(s4.z, ob[i], scp[2]);
    scp[3] = fmaf(s4.w, ob[i], scp[3]);
  }
#pragma unroll
  for (int oo = 0; oo < 4; ++oo) {
    part[wv][oo][px] = acc[oo];
    part2[wv][oo][px] = scp[oo];
  }
  __syncthreads();
  int oc = t >> 6;
  float s  = (part[0][oc][px] + part[1][oc][px]) + (part[2][oc][px] + part[3][oc][px]);
  float sc = (part2[0][oc][px] + part2[1][oc][px]) + (part2[2][oc][px] + part2[3][oc][px]);
  const float* go = ws + GO_OFF + (size_t)b * CN;
  size_t pix = (size_t)row * 64 + px;
  float gvv = go[(size_t)(o0 + oc) * N_ + pix];
  out[(size_t)b * CN + (size_t)(o0 + oc) * N_ + pix] =
      (s + c2b[o0 + oc]) + (sc + scb[o0 + oc]) * gvv;
}

extern "C" void kernel_launch(void* const* d_in, const int* in_sizes, int n_in,
                              void* d_out, int out_size, void* d_ws, size_t ws_size,
                              hipStream_t stream) {
  const float* x     = (const float*)d_in[0];
  const float* guide = (const float*)d_in[1];
  const float* lin_w = (const float*)d_in[2];
  const float* lin_b = (const float*)d_in[3];
  const float* cw    = (const float*)d_in[4];
  const float* xq_w  = (const float*)d_in[5];
  const float* xq_b  = (const float*)d_in[6];
  const float* xk_w  = (const float*)d_in[7];
  const float* xk_b  = (const float*)d_in[8];
  const float* xv_w  = (const float*)d_in[9];
  const float* xv_b  = (const float*)d_in[10];
  const float* gq_w  = (const float*)d_in[11];
  const float* gq_b  = (const float*)d_in[12];
  const float* gk_w  = (const float*)d_in[13];
  const float* gk_b  = (const float*)d_in[14];
  const float* gamma = (const float*)d_in[15];
  const float* alpha = (const float*)d_in[16];
  const float* c1_w  = (const float*)d_in[17];
  const float* c1_b  = (const float*)d_in[18];
  const float* c2_w  = (const float*)d_in[19];
  const float* c2_b  = (const float*)d_in[20];
  const float* sc_w  = (const float*)d_in[21];
  const float* sc_b  = (const float*)d_in[22];
  float* out = (float*)d_out;
  float* ws = (float*)d_ws;

  k_ca<<<256, 64, 0, stream>>>(x, guide, lin_w, lin_b, ws);
  k_coordconv<<<4096, 256, 0, stream>>>(x, guide, cw, ws);
  k_proj<<<640, 256, 0, stream>>>(ws, xq_w, xq_b, xk_w, xk_b, xv_w, xv_b,
                                  gq_w, gq_b, gk_w, gk_b);
  k_attn<<<512, 256, 0, stream>>>(ws);
  k_merge<<<512, 256, 0, stream>>>(ws, gamma, alpha);
  k_conv1<<<2048, 256, 0, stream>>>(ws, c1_w, c1_b);
  k_final<<<2048, 256, 0, stream>>>(ws, c2_w, c2_b, sc_w, sc_b, out);
}